// Round 12
// baseline (366.841 us; speedup 1.0000x reference)
//
#include <hip/hip_runtime.h>

typedef __attribute__((ext_vector_type(8))) short short8;
typedef __attribute__((ext_vector_type(4))) float f32x4;
typedef __attribute__((ext_vector_type(2))) unsigned int u32x2;

#define TTOK 10000
#define SBAR() __builtin_amdgcn_sched_barrier(0)

__device__ __forceinline__ unsigned pkbf(float lo, float hi){
  unsigned r;
  asm("v_cvt_pk_bf16_f32 %0, %1, %2" : "=v"(r) : "v"(lo), "v"(hi));
  return r;
}
__device__ __forceinline__ float ulo(unsigned p){ return __uint_as_float(p<<16); }
__device__ __forceinline__ float uhi(unsigned p){ return __uint_as_float(p&0xffff0000u); }

__device__ __forceinline__ unsigned short f2b(float f){
  unsigned x = __float_as_uint(f);
  unsigned r = (x + 0x7fffu + ((x>>16)&1u)) >> 16; // RNE
  return (unsigned short)r;
}

// ---------------- prep: bf16 weights, hb+t*tw seeds, c vector ----------------
__global__ void cnf_prep(const float* __restrict__ h, const float* __restrict__ Wx,
                         const float* __restrict__ wxt, const float* __restrict__ bx,
                         const float* __restrict__ Wh, const float* __restrict__ wht,
                         const float* __restrict__ bh, const float* __restrict__ W2,
                         float* __restrict__ hbt, float* __restrict__ cv,
                         unsigned short* __restrict__ wxb, unsigned short* __restrict__ w2b)
{
  const int b = blockIdx.x, t = threadIdx.x;
  if (b < 8) {
    for (int i=0;i<8;++i){ int idx = b*2048 + i*256 + t; wxb[idx] = f2b(Wx[idx]); }
  } else if (b < 16) {
    for (int i=0;i<8;++i){ int idx = (b-8)*2048 + i*256 + t; w2b[idx] = f2b(W2[idx]); }
  } else if (b < 18) {
    for (int i=0;i<4;++i){
      int idx = i*256 + t;
      int sb = (b-16)*8 + (idx>>7);
      int j  = idx & 127;
      float a = 0.f;
      for (int e2=0;e2<128;++e2) a += h[sb*128+e2]*Wh[j*128+e2];
      float base = a + bh[j] + bx[j];
      float tw   = wxt[j] + wht[j];
      for (int ti=0; ti<5; ++ti)
        hbt[(ti*16+sb)*128 + j] = base + 0.25f*(float)ti*tw;   // t in {0,.25,.5,.75,1}
    }
  } else {
    if (t < 128){
      float a = 0.f;
      for (int i=0;i<128;++i) a += W2[i*128+t]*Wx[t*128+i];
      cv[t] = a;
    }
  }
}

// ---------------- fused CNF main kernel ----------------
// Rounds 10/11 lesson: the 64KB weight copy per block caps any <=512-thread
// block at 8 waves/CU (both 2x4-wave and 1x8-wave land at ~22% occupancy).
// Fix: 1024-thread block = 16 waves = 8 tiles x 2 h-split waves over ONE
// weight copy. LDS = 64KB weights + 8x(4+4)KB separate z^T/sp^T = 128KB ->
// 1 block/CU, 16 waves/CU = 4 waves/SIMD (2x round 10). Per-wave dataflow
// and 2-barrier/eval structure identical to round 10 (proven 92-reg,
// no-spill). (1024,1) forces <=128 regs/wave by residency.
__global__ __launch_bounds__(1024, 1) void cnf_main(
    const float* __restrict__ emb, const float* __restrict__ lp0,
    const float* __restrict__ b2g, const float* __restrict__ hbt,
    const float* __restrict__ cg,  const unsigned short* __restrict__ wxb,
    const unsigned short* __restrict__ w2b, float* __restrict__ out)
{
  __shared__ __align__(16) unsigned short sWx[16384];
  __shared__ __align__(16) unsigned short sW2[16384];
  __shared__ __align__(16) unsigned short sZ[8][2048];   // per-tile z^T (4KB)
  __shared__ __align__(16) unsigned short sP[8][2048];   // per-tile sp^T (4KB)

  const int tid = threadIdx.x;
  const int rowbase = blockIdx.x*128;

  // stage weights into LDS with XOR swizzle (row&7)<<4 (verified rounds 1-11)
  for (int it=0; it<2; ++it){
    int L = it*16384 + tid*16;
    int hrow = L >> 8;
    int dst = L ^ ((hrow&7)<<4);
    *(int4*)((char*)sWx + dst) = *(const int4*)((const char*)wxb + L);
    *(int4*)((char*)sW2 + dst) = *(const int4*)((const char*)w2b + L);
  }
  __syncthreads();

  const int w = tid>>6, tile = w>>1, hw = w&1, l = tid&63, q = l&15, g = l>>4;
  char* zB = (char*)&sZ[tile][0];
  char* pB = (char*)&sP[tile][0];
  const int cwB = q*16 + 8*(g&1) + 256*(g>>1);  // transpose write base (bytes), + slot*512
  const int crB = g*256 + q*16;                 // transpose read base (bytes), + kc*1024
  const int wsw = (q&7)<<4;                     // weight-read swizzle
  const int qg  = q*256 + g*16;                 // weight-read lane offset (bytes)
  const int hof = hw*64 + 4*g;                  // h/e base for this wave: + 16*j + r

  const int row = rowbase + tile*16 + q;
  const int sb  = row/TTOK, tt = row - sb*TTOK;

  unsigned zbp[4][2];        // z state (this wave's e-half), packed bf16 (8 VGPRs)
  unsigned ksp[4][2];        // RK4 running sum, packed bf16 (8 VGPRs)
  f32x4 wk[4];
  float dlt = 0.f;

  // z0 = emb[t] for this wave's e-half (slot e = hof + 16*j + r, col q)
  #pragma unroll
  for (int j=0; j<4; ++j){
    f32x4 e4 = *(const f32x4*)(emb + tt*128 + hof + 16*j);
    zbp[j][0] = pkbf(e4[0], e4[1]);
    zbp[j][1] = pkbf(e4[2], e4[3]);
    wk[j] = (f32x4){0.f,0.f,0.f,0.f};
    ksp[j][0] = 0u; ksp[j][1] = 0u;
  }

  #pragma unroll 1
  for (int se=0; se<8; ++se){
    const int   s    = se>>2, e = se&3;
    const float coef = (e==0)?0.f:((e==3)?0.5f:0.25f); // z_eval = z_base + coef*k_prev
    const float we   = (e==1||e==2)?2.f:1.f;
    const int   ti   = 2*s + ((e==0)?0:((e<3)?1:2));

    // ---- phase 1: pack z_eval (this wave's 4 slots) -> shared z^T buffer
    #pragma unroll
    for (int j=0; j<4; ++j){
      u32x2 wv;
      if (e==0){
        wv[0] = zbp[j][0]; wv[1] = zbp[j][1];
      } else {
        float v0 = fmaf(coef, wk[j][0], ulo(zbp[j][0]));
        float v1 = fmaf(coef, wk[j][1], uhi(zbp[j][0]));
        float v2 = fmaf(coef, wk[j][2], ulo(zbp[j][1]));
        float v3 = fmaf(coef, wk[j][3], uhi(zbp[j][1]));
        wv[0] = pkbf(v0,v1); wv[1] = pkbf(v2,v3);
      }
      int W = (hw*4+j)*512 + cwB;
      W ^= ((W>>8)&7)<<4;
      *(u32x2*)(zB + W) = wv;
    }
    SBAR();
    __syncthreads();   // z^T complete (both halves)

    // ---- phase 2: seed acc with hb + t*tw (global, L2-resident)
    {
      const float* hb = hbt + (ti*16 + sb)*128 + hof;
      #pragma unroll
      for (int j=0; j<4; ++j)
        wk[j] = *(const f32x4*)(hb + 16*j);
    }
    SBAR();

    // ---- phase 3: matmul1 (h-half): pre = Wx[h-half] . zT(full K)
    #pragma unroll
    for (int kc=0; kc<4; ++kc){
      int R = kc*1024 + crB;
      R ^= ((R>>8)&7)<<4;
      short8 zf = *(const short8*)(zB + R);
      #pragma unroll
      for (int j=0; j<4; ++j){
        const int off = (((hw*4+j)*4096) + kc*64 + qg) ^ wsw;
        short8 af = *(const short8*)((const char*)sWx + off);
        wk[j] = __builtin_amdgcn_mfma_f32_16x16x32_bf16(af, zf, wk[j], 0,0,0);
      }
      SBAR();
    }

    // ---- phase 4: softplus -> sp^T half into shared buffer, sigmoid*c -> div
    float dv = 0.f;
    #pragma unroll
    for (int j=0; j<4; ++j){
      f32x4 cc = *(const f32x4*)(cg + hof + 16*j);
      float spv[4];
      #pragma unroll
      for (int r=0;r<4;++r){
        float x  = wk[j][r];
        float ax = __builtin_fabsf(x);
        float ea = __expf(-ax);
        float opa = 1.0f + ea;
        float rc = __builtin_amdgcn_rcpf(opa);
        float lg = __logf(opa);
        spv[r] = fmaxf(x,0.f) + lg;                 // softplus
        float sg = (x >= 0.f) ? rc : ea*rc;         // sigmoid
        dv += sg*cc[r];
      }
      int W = (hw*4+j)*512 + cwB;
      W ^= ((W>>8)&7)<<4;
      u32x2 wv = { pkbf(spv[0],spv[1]), pkbf(spv[2],spv[3]) };
      *(u32x2*)(pB + W) = wv;
    }
    dlt += we*dv;
    SBAR();
    __syncthreads();   // sp^T complete (both halves)

    // ---- phase 5: matmul2 (o-half): dz = W2[o-half] . spT(full K), seeded b2
    #pragma unroll
    for (int j=0; j<4; ++j)
      wk[j] = *(const f32x4*)(b2g + hof + 16*j);
    SBAR();
    #pragma unroll
    for (int kc=0; kc<4; ++kc){
      int R = kc*1024 + crB;
      R ^= ((R>>8)&7)<<4;
      short8 sf = *(const short8*)(pB + R);
      #pragma unroll
      for (int j=0; j<4; ++j){
        const int off = (((hw*4+j)*4096) + kc*64 + qg) ^ wsw;
        short8 af = *(const short8*)((const char*)sW2 + off);
        wk[j] = __builtin_amdgcn_mfma_f32_16x16x32_bf16(af, sf, wk[j], 0,0,0);
      }
      SBAR();
    }

    // ---- phase 6: RK4 accumulate (this wave's e-half; wk = k_e)
    if (e==0){
      #pragma unroll
      for (int j=0;j<4;++j){
        ksp[j][0] = pkbf(wk[j][0], wk[j][1]);
        ksp[j][1] = pkbf(wk[j][2], wk[j][3]);
      }
    } else if (e<3){
      #pragma unroll
      for (int j=0;j<4;++j){
        float a0 = fmaf(we, wk[j][0], ulo(ksp[j][0]));
        float a1 = fmaf(we, wk[j][1], uhi(ksp[j][0]));
        float a2 = fmaf(we, wk[j][2], ulo(ksp[j][1]));
        float a3 = fmaf(we, wk[j][3], uhi(ksp[j][1]));
        ksp[j][0] = pkbf(a0,a1);
        ksp[j][1] = pkbf(a2,a3);
      }
    } else {
      // z += (ks + k4)/12
      #pragma unroll
      for (int j=0;j<4;++j){
        float a0 = fmaf(1.f/12.f, ulo(ksp[j][0]) + wk[j][0], ulo(zbp[j][0]));
        float a1 = fmaf(1.f/12.f, uhi(ksp[j][0]) + wk[j][1], uhi(zbp[j][0]));
        float a2 = fmaf(1.f/12.f, ulo(ksp[j][1]) + wk[j][2], ulo(zbp[j][1]));
        float a3 = fmaf(1.f/12.f, uhi(ksp[j][1]) + wk[j][3], uhi(zbp[j][1]));
        zbp[j][0] = pkbf(a0,a1);
        zbp[j][1] = pkbf(a2,a3);
      }
    }
    SBAR();
  }

  // ---- epilogue: g-reduce div partials, cross-wave combine via LDS (reuse zB)
  {
    float d = dlt;
    d += __shfl_xor(d, 16, 64);
    d += __shfl_xor(d, 32, 64);
    float* fDv = (float*)zB;
    if (g==0) fDv[hw*16 + q] = d;
    __syncthreads();
    if (hw==0 && g==0){
      float dt = (fDv[q] + fDv[16+q]) * (1.f/12.f);
      out[row] = lp0[row] - dt;
    }
  }
}

extern "C" void kernel_launch(void* const* d_in, const int* in_sizes, int n_in,
                              void* d_out, int out_size, void* d_ws, size_t ws_size,
                              hipStream_t stream) {
  const float* h    = (const float*)d_in[0];
  const float* emb  = (const float*)d_in[1];
  const float* lp0  = (const float*)d_in[2];
  const float* Wx   = (const float*)d_in[3];
  const float* wxt  = (const float*)d_in[4];
  const float* bx   = (const float*)d_in[5];
  const float* Wh   = (const float*)d_in[6];
  const float* wht  = (const float*)d_in[7];
  const float* bh   = (const float*)d_in[8];
  const float* W2   = (const float*)d_in[9];
  const float* b2   = (const float*)d_in[10];
  float* out = (float*)d_out;

  char* ws = (char*)d_ws;
  float* hbt          = (float*)ws;            // 5*16*128 f32 = 40960 B
  float* cv           = (float*)(ws + 40960);  // 128 f32     = 512 B
  unsigned short* wxb = (unsigned short*)(ws + 41472); // 16384 bf16 = 32768 B
  unsigned short* w2b = (unsigned short*)(ws + 74240); // 16384 bf16 = 32768 B

  cnf_prep<<<19, 256, 0, stream>>>(h, Wx, wxt, bx, Wh, wht, bh, W2, hbt, cv, wxb, w2b);
  cnf_main<<<1250, 1024, 0, stream>>>(emb, lp0, b2, hbt, cv, wxb, w2b, out);
}

// Round 13
// 245.065 us; speedup vs baseline: 1.4969x; 1.4969x over previous
//
#include <hip/hip_runtime.h>

typedef __attribute__((ext_vector_type(8))) short short8;
typedef __attribute__((ext_vector_type(4))) float f32x4;
typedef __attribute__((ext_vector_type(2))) unsigned int u32x2;

#define TTOK 10000
#define SBAR() __builtin_amdgcn_sched_barrier(0)

__device__ __forceinline__ unsigned pkbf(float lo, float hi){
  unsigned r;
  asm("v_cvt_pk_bf16_f32 %0, %1, %2" : "=v"(r) : "v"(lo), "v"(hi));
  return r;
}
__device__ __forceinline__ float ulo(unsigned p){ return __uint_as_float(p<<16); }
__device__ __forceinline__ float uhi(unsigned p){ return __uint_as_float(p&0xffff0000u); }

__device__ __forceinline__ unsigned short f2b(float f){
  unsigned x = __float_as_uint(f);
  unsigned r = (x + 0x7fffu + ((x>>16)&1u)) >> 16; // RNE
  return (unsigned short)r;
}

// ---------------- prep: fragment-linear bf16 weights, hb+t*tw seeds, c ----------------
// Weight layout (round-13): wb[((jj*4+kc)*64 + l)*8 + i] = W[jj*16+q][kc*32+g*8+i],
// l = g*16+q. A wave's ds_read_b128 for fragment (jj,kc) is then 64 lanes x
// contiguous 16B = 1024B linear -> bank-conflict-free, and the LDS address is
// wave-base + compile-time immediate (kills the old 8-way aliased q*256^swz).
__global__ void cnf_prep(const float* __restrict__ h, const float* __restrict__ Wx,
                         const float* __restrict__ wxt, const float* __restrict__ bx,
                         const float* __restrict__ Wh, const float* __restrict__ wht,
                         const float* __restrict__ bh, const float* __restrict__ W2,
                         float* __restrict__ hbt, float* __restrict__ cv,
                         unsigned short* __restrict__ wxb, unsigned short* __restrict__ w2b)
{
  const int b = blockIdx.x, t = threadIdx.x;
  if (b < 16) {
    const int jj = b & 7;
    const float* W = (b < 8) ? Wx : W2;
    unsigned short* dst = (b < 8) ? wxb : w2b;
    const int kc = t>>6, l = t&63, q = l&15, g = l>>4;
    #pragma unroll
    for (int i=0;i<8;++i)
      dst[((jj*4+kc)*64 + l)*8 + i] = f2b(W[(jj*16+q)*128 + kc*32 + g*8 + i]);
  } else if (b < 18) {
    for (int i=0;i<4;++i){
      int idx = i*256 + t;
      int sb = (b-16)*8 + (idx>>7);
      int j  = idx & 127;
      float a = 0.f;
      for (int e2=0;e2<128;++e2) a += h[sb*128+e2]*Wh[j*128+e2];
      float base = a + bh[j] + bx[j];
      float tw   = wxt[j] + wht[j];
      for (int ti=0; ti<5; ++ti)
        hbt[(ti*16+sb)*128 + j] = base + 0.25f*(float)ti*tw;   // t in {0,.25,.5,.75,1}
    }
  } else {
    if (t < 128){
      float a = 0.f;
      for (int i=0;i<128;++i) a += W2[i*128+t]*Wx[t*128+i];
      cv[t] = a;
    }
  }
}

// ---------------- fused CNF main kernel ----------------
// Round-10 champion structure (256 thr = 2 tiles x 2 h-split waves, 92 reg,
// no spill, 2 blocks/CU) + round-13 change: fragment-linear weight LDS.
// Weight reads: lane-linear (conflict-free) with immediate offsets.
__global__ __launch_bounds__(256, 2) void cnf_main(
    const float* __restrict__ emb, const float* __restrict__ lp0,
    const float* __restrict__ b2g, const float* __restrict__ hbt,
    const float* __restrict__ cg,  const unsigned short* __restrict__ wxb,
    const unsigned short* __restrict__ w2b, float* __restrict__ out)
{
  __shared__ __align__(16) unsigned short sWx[16384];
  __shared__ __align__(16) unsigned short sW2[16384];
  __shared__ __align__(16) unsigned short sZ[2][2048];   // per-tile z^T (4KB)
  __shared__ __align__(16) unsigned short sP[2][2048];   // per-tile sp^T (4KB)

  const int tid = threadIdx.x;
  const int rowbase = blockIdx.x*32;

  // stage weights into LDS: plain linear copy (layout already fragment-linear)
  for (int it=0; it<8; ++it){
    int L = it*4096 + tid*16;
    *(int4*)((char*)sWx + L) = *(const int4*)((const char*)wxb + L);
    *(int4*)((char*)sW2 + L) = *(const int4*)((const char*)w2b + L);
  }
  __syncthreads();

  const int w = tid>>6, tile = w>>1, hw = w&1, l = tid&63, q = l&15, g = l>>4;
  char* zB = (char*)&sZ[tile][0];
  char* pB = (char*)&sP[tile][0];
  const char* wxBase = (const char*)sWx + hw*16384 + l*16;  // + (j*4+kc)*1024 imm
  const char* w2Base = (const char*)sW2 + hw*16384 + l*16;
  const int cwB = q*16 + 8*(g&1) + 256*(g>>1);  // transpose write base (bytes), + slot*512
  const int crB = g*256 + q*16;                 // transpose read base (bytes), + kc*1024
  const int hof = hw*64 + 4*g;                  // h/e base for this wave: + 16*j + r

  const int row = rowbase + tile*16 + q;
  const int sb  = row/TTOK, tt = row - sb*TTOK;

  unsigned zbp[4][2];        // z state (this wave's e-half), packed bf16 (8 VGPRs)
  unsigned ksp[4][2];        // RK4 running sum, packed bf16 (8 VGPRs)
  f32x4 wk[4];
  float dlt = 0.f;

  // z0 = emb[t] for this wave's e-half (slot e = hof + 16*j + r, col q)
  #pragma unroll
  for (int j=0; j<4; ++j){
    f32x4 e4 = *(const f32x4*)(emb + tt*128 + hof + 16*j);
    zbp[j][0] = pkbf(e4[0], e4[1]);
    zbp[j][1] = pkbf(e4[2], e4[3]);
    wk[j] = (f32x4){0.f,0.f,0.f,0.f};
    ksp[j][0] = 0u; ksp[j][1] = 0u;
  }

  #pragma unroll 1
  for (int se=0; se<8; ++se){
    const int   s    = se>>2, e = se&3;
    const float coef = (e==0)?0.f:((e==3)?0.5f:0.25f); // z_eval = z_base + coef*k_prev
    const float we   = (e==1||e==2)?2.f:1.f;
    const int   ti   = 2*s + ((e==0)?0:((e<3)?1:2));

    // ---- phase 1: pack z_eval (this wave's 4 slots) -> shared z^T buffer
    #pragma unroll
    for (int j=0; j<4; ++j){
      u32x2 wv;
      if (e==0){
        wv[0] = zbp[j][0]; wv[1] = zbp[j][1];
      } else {
        float v0 = fmaf(coef, wk[j][0], ulo(zbp[j][0]));
        float v1 = fmaf(coef, wk[j][1], uhi(zbp[j][0]));
        float v2 = fmaf(coef, wk[j][2], ulo(zbp[j][1]));
        float v3 = fmaf(coef, wk[j][3], uhi(zbp[j][1]));
        wv[0] = pkbf(v0,v1); wv[1] = pkbf(v2,v3);
      }
      int W = (hw*4+j)*512 + cwB;
      W ^= ((W>>8)&7)<<4;
      *(u32x2*)(zB + W) = wv;
    }
    SBAR();
    __syncthreads();   // z^T complete (both halves)

    // ---- phase 2: seed acc with hb + t*tw (global, L2-resident)
    {
      const float* hb = hbt + (ti*16 + sb)*128 + hof;
      #pragma unroll
      for (int j=0; j<4; ++j)
        wk[j] = *(const f32x4*)(hb + 16*j);
    }
    SBAR();

    // ---- phase 3: matmul1 (h-half): pre = Wx[h-half] . zT(full K)
    #pragma unroll
    for (int kc=0; kc<4; ++kc){
      int R = kc*1024 + crB;
      R ^= ((R>>8)&7)<<4;
      short8 zf = *(const short8*)(zB + R);
      #pragma unroll
      for (int j=0; j<4; ++j){
        short8 af = *(const short8*)(wxBase + (j*4+kc)*1024);
        wk[j] = __builtin_amdgcn_mfma_f32_16x16x32_bf16(af, zf, wk[j], 0,0,0);
      }
      SBAR();
    }

    // ---- phase 4: softplus -> sp^T half into shared buffer, sigmoid*c -> div
    float dv = 0.f;
    #pragma unroll
    for (int j=0; j<4; ++j){
      f32x4 cc = *(const f32x4*)(cg + hof + 16*j);
      float spv[4];
      #pragma unroll
      for (int r=0;r<4;++r){
        float x  = wk[j][r];
        float ax = __builtin_fabsf(x);
        float ea = __expf(-ax);
        float opa = 1.0f + ea;
        float rc = __builtin_amdgcn_rcpf(opa);
        float lg = __logf(opa);
        spv[r] = fmaxf(x,0.f) + lg;                 // softplus
        float sg = (x >= 0.f) ? rc : ea*rc;         // sigmoid
        dv += sg*cc[r];
      }
      int W = (hw*4+j)*512 + cwB;
      W ^= ((W>>8)&7)<<4;
      u32x2 wv = { pkbf(spv[0],spv[1]), pkbf(spv[2],spv[3]) };
      *(u32x2*)(pB + W) = wv;
    }
    dlt += we*dv;
    SBAR();
    __syncthreads();   // sp^T complete (both halves)

    // ---- phase 5: matmul2 (o-half): dz = W2[o-half] . spT(full K), seeded b2
    #pragma unroll
    for (int j=0; j<4; ++j)
      wk[j] = *(const f32x4*)(b2g + hof + 16*j);
    SBAR();
    #pragma unroll
    for (int kc=0; kc<4; ++kc){
      int R = kc*1024 + crB;
      R ^= ((R>>8)&7)<<4;
      short8 sf = *(const short8*)(pB + R);
      #pragma unroll
      for (int j=0; j<4; ++j){
        short8 af = *(const short8*)(w2Base + (j*4+kc)*1024);
        wk[j] = __builtin_amdgcn_mfma_f32_16x16x32_bf16(af, sf, wk[j], 0,0,0);
      }
      SBAR();
    }

    // ---- phase 6: RK4 accumulate (this wave's e-half; wk = k_e)
    if (e==0){
      #pragma unroll
      for (int j=0;j<4;++j){
        ksp[j][0] = pkbf(wk[j][0], wk[j][1]);
        ksp[j][1] = pkbf(wk[j][2], wk[j][3]);
      }
    } else if (e<3){
      #pragma unroll
      for (int j=0;j<4;++j){
        float a0 = fmaf(we, wk[j][0], ulo(ksp[j][0]));
        float a1 = fmaf(we, wk[j][1], uhi(ksp[j][0]));
        float a2 = fmaf(we, wk[j][2], ulo(ksp[j][1]));
        float a3 = fmaf(we, wk[j][3], uhi(ksp[j][1]));
        ksp[j][0] = pkbf(a0,a1);
        ksp[j][1] = pkbf(a2,a3);
      }
    } else {
      // z += (ks + k4)/12
      #pragma unroll
      for (int j=0;j<4;++j){
        float a0 = fmaf(1.f/12.f, ulo(ksp[j][0]) + wk[j][0], ulo(zbp[j][0]));
        float a1 = fmaf(1.f/12.f, uhi(ksp[j][0]) + wk[j][1], uhi(zbp[j][0]));
        float a2 = fmaf(1.f/12.f, ulo(ksp[j][1]) + wk[j][2], ulo(zbp[j][1]));
        float a3 = fmaf(1.f/12.f, uhi(ksp[j][1]) + wk[j][3], uhi(zbp[j][1]));
        zbp[j][0] = pkbf(a0,a1);
        zbp[j][1] = pkbf(a2,a3);
      }
    }
    SBAR();
  }

  // ---- epilogue: g-reduce div partials, cross-wave combine via LDS (reuse zB)
  {
    float d = dlt;
    d += __shfl_xor(d, 16, 64);
    d += __shfl_xor(d, 32, 64);
    float* fDv = (float*)zB;
    if (g==0) fDv[hw*16 + q] = d;
    __syncthreads();
    if (hw==0 && g==0){
      float dt = (fDv[q] + fDv[16+q]) * (1.f/12.f);
      out[row] = lp0[row] - dt;
    }
  }
}

extern "C" void kernel_launch(void* const* d_in, const int* in_sizes, int n_in,
                              void* d_out, int out_size, void* d_ws, size_t ws_size,
                              hipStream_t stream) {
  const float* h    = (const float*)d_in[0];
  const float* emb  = (const float*)d_in[1];
  const float* lp0  = (const float*)d_in[2];
  const float* Wx   = (const float*)d_in[3];
  const float* wxt  = (const float*)d_in[4];
  const float* bx   = (const float*)d_in[5];
  const float* Wh   = (const float*)d_in[6];
  const float* wht  = (const float*)d_in[7];
  const float* bh   = (const float*)d_in[8];
  const float* W2   = (const float*)d_in[9];
  const float* b2   = (const float*)d_in[10];
  float* out = (float*)d_out;

  char* ws = (char*)d_ws;
  float* hbt          = (float*)ws;            // 5*16*128 f32 = 40960 B
  float* cv           = (float*)(ws + 40960);  // 128 f32     = 512 B
  unsigned short* wxb = (unsigned short*)(ws + 41472); // 16384 bf16 = 32768 B
  unsigned short* w2b = (unsigned short*)(ws + 74240); // 16384 bf16 = 32768 B

  cnf_prep<<<19, 256, 0, stream>>>(h, Wx, wxt, bx, Wh, wht, bh, W2, hbt, cv, wxb, w2b);
  cnf_main<<<5000, 256, 0, stream>>>(emb, lp0, b2, hbt, cv, wxb, w2b, out);
}

// Round 14
// 224.029 us; speedup vs baseline: 1.6375x; 1.0939x over previous
//
#include <hip/hip_runtime.h>

typedef __attribute__((ext_vector_type(8))) short short8;
typedef __attribute__((ext_vector_type(4))) float f32x4;
typedef __attribute__((ext_vector_type(2))) unsigned int u32x2;

#define TTOK 10000
#define SBAR() __builtin_amdgcn_sched_barrier(0)

__device__ __forceinline__ unsigned pkbf(float lo, float hi){
  unsigned r;
  asm("v_cvt_pk_bf16_f32 %0, %1, %2" : "=v"(r) : "v"(lo), "v"(hi));
  return r;
}
__device__ __forceinline__ float ulo(unsigned p){ return __uint_as_float(p<<16); }
__device__ __forceinline__ float uhi(unsigned p){ return __uint_as_float(p&0xffff0000u); }

__device__ __forceinline__ unsigned short f2b(float f){
  unsigned x = __float_as_uint(f);
  unsigned r = (x + 0x7fffu + ((x>>16)&1u)) >> 16; // RNE
  return (unsigned short)r;
}

// ---------------- prep: fragment-linear bf16 weights, hb+t*tw seeds, c ----------------
// wb[((jj*4+kc)*64 + l)*8 + i] = W[jj*16+q][kc*32+g*8+i], l=g*16+q: a wave's
// ds_read_b128 per fragment is 64 lanes x contiguous 16B (conflict-free),
// address = wave-base + immediate (round 13, verified).
__global__ void cnf_prep(const float* __restrict__ h, const float* __restrict__ Wx,
                         const float* __restrict__ wxt, const float* __restrict__ bx,
                         const float* __restrict__ Wh, const float* __restrict__ wht,
                         const float* __restrict__ bh, const float* __restrict__ W2,
                         float* __restrict__ hbt, float* __restrict__ cv,
                         unsigned short* __restrict__ wxb, unsigned short* __restrict__ w2b)
{
  const int b = blockIdx.x, t = threadIdx.x;
  if (b < 16) {
    const int jj = b & 7;
    const float* W = (b < 8) ? Wx : W2;
    unsigned short* dst = (b < 8) ? wxb : w2b;
    const int kc = t>>6, l = t&63, q = l&15, g = l>>4;
    #pragma unroll
    for (int i=0;i<8;++i)
      dst[((jj*4+kc)*64 + l)*8 + i] = f2b(W[(jj*16+q)*128 + kc*32 + g*8 + i]);
  } else if (b < 18) {
    for (int i=0;i<4;++i){
      int idx = i*256 + t;
      int sb = (b-16)*8 + (idx>>7);
      int j  = idx & 127;
      float a = 0.f;
      for (int e2=0;e2<128;++e2) a += h[sb*128+e2]*Wh[j*128+e2];
      float base = a + bh[j] + bx[j];
      float tw   = wxt[j] + wht[j];
      for (int ti=0; ti<5; ++ti)
        hbt[(ti*16+sb)*128 + j] = base + 0.25f*(float)ti*tw;   // t in {0,.25,.5,.75,1}
    }
  } else {
    if (t < 128){
      float a = 0.f;
      for (int i=0;i<128;++i) a += W2[i*128+t]*Wx[t*128+i];
      cv[t] = a;
    }
  }
}

// ---------------- fused CNF main kernel ----------------
// Round-14 structure: 256 thr = 4 waves; wave (tg,hw) handles the hw h-half
// of TWO tiles (2tg, 2tg+1). Each weight fragment read feeds 2 MFMAs
// (halves LDS weight traffic vs round 13); per-tile 4KB buffer time-shares
// z^T then sp^T (4 barriers/eval over 2x work = round-10 per-work cost).
// hb seed prefetched in phase 1 (latency hidden under pack+barrier); b2
// persistent in regs. LDS 64KB weights + 16KB bufs = 80KB -> 2 blocks/CU.
__global__ __launch_bounds__(256, 2) void cnf_main(
    const float* __restrict__ emb, const float* __restrict__ lp0,
    const float* __restrict__ b2g, const float* __restrict__ hbt,
    const float* __restrict__ cg,  const unsigned short* __restrict__ wxb,
    const unsigned short* __restrict__ w2b, float* __restrict__ out)
{
  __shared__ __align__(16) unsigned short sWx[16384];
  __shared__ __align__(16) unsigned short sW2[16384];
  __shared__ __align__(16) unsigned short sT[4][2048];   // per-tile timeshared z^T/sp^T (4KB)

  const int tid = threadIdx.x;
  const int rowbase = blockIdx.x*64;

  // stage weights into LDS: plain linear copy (layout already fragment-linear)
  for (int it=0; it<8; ++it){
    int L = it*4096 + tid*16;
    *(int4*)((char*)sWx + L) = *(const int4*)((const char*)wxb + L);
    *(int4*)((char*)sW2 + L) = *(const int4*)((const char*)w2b + L);
  }
  __syncthreads();

  const int w = tid>>6, tg = w>>1, hw = w&1, l = tid&63, q = l&15, g = l>>4;
  char* zB0 = (char*)&sT[2*tg][0];
  char* zB1 = (char*)&sT[2*tg+1][0];
  const char* wxBase = (const char*)sWx + hw*16384 + l*16;  // + (j*4+kc)*1024 imm
  const char* w2Base = (const char*)sW2 + hw*16384 + l*16;
  const int cwB = q*16 + 8*(g&1) + 256*(g>>1);  // transpose write base (bytes), + slot*512
  const int crB = g*256 + q*16;                 // transpose read base (bytes), + kc*1024
  const int hof = hw*64 + 4*g;                  // h/e base for this wave: + 16*j + r

  const int row0 = rowbase + tg*32 + q;
  const int row1 = row0 + 16;
  const int sb0 = row0/TTOK, tt0 = row0 - sb0*TTOK;
  const int sb1 = row1/TTOK, tt1 = row1 - sb1*TTOK;

  unsigned zbp0[4][2], zbp1[4][2];   // z state, packed bf16 (16 VGPRs)
  unsigned ksp0[4][2], ksp1[4][2];   // RK4 running sum, packed bf16 (16 VGPRs)
  f32x4 wk0[4], wk1[4];              // accumulators (32, acc file)
  f32x4 b2r[4];                      // persistent b2 (16 VGPRs)
  float dlt0 = 0.f, dlt1 = 0.f;

  #pragma unroll
  for (int j=0; j<4; ++j){
    f32x4 e0 = *(const f32x4*)(emb + tt0*128 + hof + 16*j);
    f32x4 e1 = *(const f32x4*)(emb + tt1*128 + hof + 16*j);
    zbp0[j][0] = pkbf(e0[0], e0[1]);  zbp0[j][1] = pkbf(e0[2], e0[3]);
    zbp1[j][0] = pkbf(e1[0], e1[1]);  zbp1[j][1] = pkbf(e1[2], e1[3]);
    wk0[j] = (f32x4){0.f,0.f,0.f,0.f};
    wk1[j] = (f32x4){0.f,0.f,0.f,0.f};
    ksp0[j][0] = 0u; ksp0[j][1] = 0u;
    ksp1[j][0] = 0u; ksp1[j][1] = 0u;
    b2r[j] = *(const f32x4*)(b2g + hof + 16*j);
  }

  #pragma unroll 1
  for (int se=0; se<8; ++se){
    const int   s    = se>>2, e = se&3;
    const float coef = (e==0)?0.f:((e==3)?0.5f:0.25f); // z_eval = z_base + coef*k_prev
    const float we   = (e==1||e==2)?2.f:1.f;
    const int   ti   = 2*s + ((e==0)?0:((e<3)?1:2));

    // ---- phase 1: prefetch hb seeds (latency hides under pack+barrier),
    //               pack z_eval for both tiles -> z^T buffers
    f32x4 hb0[4], hb1[4];
    {
      const float* p0 = hbt + (ti*16 + sb0)*128 + hof;
      const float* p1 = hbt + (ti*16 + sb1)*128 + hof;
      #pragma unroll
      for (int j=0; j<4; ++j){
        hb0[j] = *(const f32x4*)(p0 + 16*j);
        hb1[j] = *(const f32x4*)(p1 + 16*j);
      }
    }
    #pragma unroll
    for (int j=0; j<4; ++j){
      u32x2 wv0, wv1;
      if (e==0){
        wv0[0] = zbp0[j][0]; wv0[1] = zbp0[j][1];
        wv1[0] = zbp1[j][0]; wv1[1] = zbp1[j][1];
      } else {
        float a0 = fmaf(coef, wk0[j][0], ulo(zbp0[j][0]));
        float a1 = fmaf(coef, wk0[j][1], uhi(zbp0[j][0]));
        float a2 = fmaf(coef, wk0[j][2], ulo(zbp0[j][1]));
        float a3 = fmaf(coef, wk0[j][3], uhi(zbp0[j][1]));
        wv0[0] = pkbf(a0,a1); wv0[1] = pkbf(a2,a3);
        float b0 = fmaf(coef, wk1[j][0], ulo(zbp1[j][0]));
        float b1 = fmaf(coef, wk1[j][1], uhi(zbp1[j][0]));
        float b2v= fmaf(coef, wk1[j][2], ulo(zbp1[j][1]));
        float b3 = fmaf(coef, wk1[j][3], uhi(zbp1[j][1]));
        wv1[0] = pkbf(b0,b1); wv1[1] = pkbf(b2v,b3);
      }
      int W = (hw*4+j)*512 + cwB;
      W ^= ((W>>8)&7)<<4;
      *(u32x2*)(zB0 + W) = wv0;
      *(u32x2*)(zB1 + W) = wv1;
    }
    SBAR();
    __syncthreads();   // z^T complete (both halves, both tiles)

    // ---- phase 3: matmul1 (h-half, both tiles): seed = prefetched hb
    #pragma unroll
    for (int j=0; j<4; ++j){ wk0[j] = hb0[j]; wk1[j] = hb1[j]; }
    #pragma unroll
    for (int kc=0; kc<4; ++kc){
      int R = kc*1024 + crB;
      R ^= ((R>>8)&7)<<4;
      short8 zf0 = *(const short8*)(zB0 + R);
      short8 zf1 = *(const short8*)(zB1 + R);
      #pragma unroll
      for (int j=0; j<4; ++j){
        short8 af = *(const short8*)(wxBase + (j*4+kc)*1024);
        wk0[j] = __builtin_amdgcn_mfma_f32_16x16x32_bf16(af, zf0, wk0[j], 0,0,0);
        wk1[j] = __builtin_amdgcn_mfma_f32_16x16x32_bf16(af, zf1, wk1[j], 0,0,0);
      }
      SBAR();
    }
    __syncthreads();   // z^T reads done; buffers free for sp^T

    // ---- phase 4: softplus both tiles -> sp^T buffers, sigmoid*c -> div
    float dv0 = 0.f, dv1 = 0.f;
    #pragma unroll
    for (int j=0; j<4; ++j){
      f32x4 cc = *(const f32x4*)(cg + hof + 16*j);
      float sp0[4], sp1[4];
      #pragma unroll
      for (int r=0;r<4;++r){
        float x  = wk0[j][r];
        float ax = __builtin_fabsf(x);
        float ea = __expf(-ax);
        float opa = 1.0f + ea;
        float rc = __builtin_amdgcn_rcpf(opa);
        float lg = __logf(opa);
        sp0[r] = fmaxf(x,0.f) + lg;
        float sg = (x >= 0.f) ? rc : ea*rc;
        dv0 += sg*cc[r];
        float y  = wk1[j][r];
        float ay = __builtin_fabsf(y);
        float eb = __expf(-ay);
        float opb = 1.0f + eb;
        float rb = __builtin_amdgcn_rcpf(opb);
        float lb = __logf(opb);
        sp1[r] = fmaxf(y,0.f) + lb;
        float sh = (y >= 0.f) ? rb : eb*rb;
        dv1 += sh*cc[r];
      }
      int W = (hw*4+j)*512 + cwB;
      W ^= ((W>>8)&7)<<4;
      u32x2 wv0 = { pkbf(sp0[0],sp0[1]), pkbf(sp0[2],sp0[3]) };
      u32x2 wv1 = { pkbf(sp1[0],sp1[1]), pkbf(sp1[2],sp1[3]) };
      *(u32x2*)(zB0 + W) = wv0;
      *(u32x2*)(zB1 + W) = wv1;
    }
    dlt0 += we*dv0;
    dlt1 += we*dv1;
    SBAR();
    __syncthreads();   // sp^T complete

    // ---- phase 5: matmul2 (o-half, both tiles): seed = persistent b2
    #pragma unroll
    for (int j=0; j<4; ++j){ wk0[j] = b2r[j]; wk1[j] = b2r[j]; }
    #pragma unroll
    for (int kc=0; kc<4; ++kc){
      int R = kc*1024 + crB;
      R ^= ((R>>8)&7)<<4;
      short8 sf0 = *(const short8*)(zB0 + R);
      short8 sf1 = *(const short8*)(zB1 + R);
      #pragma unroll
      for (int j=0; j<4; ++j){
        short8 af = *(const short8*)(w2Base + (j*4+kc)*1024);
        wk0[j] = __builtin_amdgcn_mfma_f32_16x16x32_bf16(af, sf0, wk0[j], 0,0,0);
        wk1[j] = __builtin_amdgcn_mfma_f32_16x16x32_bf16(af, sf1, wk1[j], 0,0,0);
      }
      SBAR();
    }

    // ---- phase 6: RK4 accumulate (both tiles; wk = k_e)
    if (e==0){
      #pragma unroll
      for (int j=0;j<4;++j){
        ksp0[j][0] = pkbf(wk0[j][0], wk0[j][1]);
        ksp0[j][1] = pkbf(wk0[j][2], wk0[j][3]);
        ksp1[j][0] = pkbf(wk1[j][0], wk1[j][1]);
        ksp1[j][1] = pkbf(wk1[j][2], wk1[j][3]);
      }
    } else if (e<3){
      #pragma unroll
      for (int j=0;j<4;++j){
        float a0 = fmaf(we, wk0[j][0], ulo(ksp0[j][0]));
        float a1 = fmaf(we, wk0[j][1], uhi(ksp0[j][0]));
        float a2 = fmaf(we, wk0[j][2], ulo(ksp0[j][1]));
        float a3 = fmaf(we, wk0[j][3], uhi(ksp0[j][1]));
        ksp0[j][0] = pkbf(a0,a1); ksp0[j][1] = pkbf(a2,a3);
        float c0 = fmaf(we, wk1[j][0], ulo(ksp1[j][0]));
        float c1 = fmaf(we, wk1[j][1], uhi(ksp1[j][0]));
        float c2 = fmaf(we, wk1[j][2], ulo(ksp1[j][1]));
        float c3 = fmaf(we, wk1[j][3], uhi(ksp1[j][1]));
        ksp1[j][0] = pkbf(c0,c1); ksp1[j][1] = pkbf(c2,c3);
      }
    } else {
      #pragma unroll
      for (int j=0;j<4;++j){
        float a0 = fmaf(1.f/12.f, ulo(ksp0[j][0]) + wk0[j][0], ulo(zbp0[j][0]));
        float a1 = fmaf(1.f/12.f, uhi(ksp0[j][0]) + wk0[j][1], uhi(zbp0[j][0]));
        float a2 = fmaf(1.f/12.f, ulo(ksp0[j][1]) + wk0[j][2], ulo(zbp0[j][1]));
        float a3 = fmaf(1.f/12.f, uhi(ksp0[j][1]) + wk0[j][3], uhi(zbp0[j][1]));
        zbp0[j][0] = pkbf(a0,a1); zbp0[j][1] = pkbf(a2,a3);
        float c0 = fmaf(1.f/12.f, ulo(ksp1[j][0]) + wk1[j][0], ulo(zbp1[j][0]));
        float c1 = fmaf(1.f/12.f, uhi(ksp1[j][0]) + wk1[j][1], uhi(zbp1[j][0]));
        float c2 = fmaf(1.f/12.f, ulo(ksp1[j][1]) + wk1[j][2], ulo(zbp1[j][1]));
        float c3 = fmaf(1.f/12.f, uhi(ksp1[j][1]) + wk1[j][3], uhi(zbp1[j][1]));
        zbp1[j][0] = pkbf(c0,c1); zbp1[j][1] = pkbf(c2,c3);
      }
    }
    SBAR();
    __syncthreads();   // sp^T reads done; buffers free for next eval's z^T
  }

  // ---- epilogue: g-reduce div partials, cross-wave combine via LDS (reuse zB0)
  {
    float d0 = dlt0, d1 = dlt1;
    d0 += __shfl_xor(d0, 16, 64);
    d0 += __shfl_xor(d0, 32, 64);
    d1 += __shfl_xor(d1, 16, 64);
    d1 += __shfl_xor(d1, 32, 64);
    float* fDv = (float*)zB0;
    if (g==0){
      fDv[hw*16 + q]      = d0;
      fDv[32 + hw*16 + q] = d1;
    }
    __syncthreads();
    if (hw==0 && g==0){
      float t0 = (fDv[q] + fDv[16+q]) * (1.f/12.f);
      float t1 = (fDv[32+q] + fDv[48+q]) * (1.f/12.f);
      out[row0] = lp0[row0] - t0;
      out[row1] = lp0[row1] - t1;
    }
  }
}

extern "C" void kernel_launch(void* const* d_in, const int* in_sizes, int n_in,
                              void* d_out, int out_size, void* d_ws, size_t ws_size,
                              hipStream_t stream) {
  const float* h    = (const float*)d_in[0];
  const float* emb  = (const float*)d_in[1];
  const float* lp0  = (const float*)d_in[2];
  const float* Wx   = (const float*)d_in[3];
  const float* wxt  = (const float*)d_in[4];
  const float* bx   = (const float*)d_in[5];
  const float* Wh   = (const float*)d_in[6];
  const float* wht  = (const float*)d_in[7];
  const float* bh   = (const float*)d_in[8];
  const float* W2   = (const float*)d_in[9];
  const float* b2   = (const float*)d_in[10];
  float* out = (float*)d_out;

  char* ws = (char*)d_ws;
  float* hbt          = (float*)ws;            // 5*16*128 f32 = 40960 B
  float* cv           = (float*)(ws + 40960);  // 128 f32     = 512 B
  unsigned short* wxb = (unsigned short*)(ws + 41472); // 16384 bf16 = 32768 B
  unsigned short* w2b = (unsigned short*)(ws + 74240); // 16384 bf16 = 32768 B

  cnf_prep<<<19, 256, 0, stream>>>(h, Wx, wxt, bx, Wh, wht, bh, W2, hbt, cv, wxb, w2b);
  cnf_main<<<2500, 256, 0, stream>>>(emb, lp0, b2, hbt, cv, wxb, w2b, out);
}